// Round 12
// baseline (66.051 us; speedup 1.0000x reference)
//
#include <hip/hip_runtime.h>

// CARAFE-style fused upsampler: B=8, C=64, H=W=128, scale=2, ks=3.
// K1: channel mean (block-reduced, float4 coalesced) -> d_ws.
// K2: full-width strips: block = (batch, 4 lo-res rows x 128 cols, 16-ch
//     group), TB=512, grid 1024, XCD-swizzled (batch-per-XCD -> halo L2 hits).
//     Staged rows are exact 512B image rows (zero col overfetch); output
//     stores are 1KB/wave (64 lanes = one full hi-res row). Left/right edge
//     taps folded into post-softmax weights (== reference zero-pad).
//     Fast-math weight path + T14 stage split as rounds 10-11.

#define TB 256

__device__ __forceinline__ float frcp(float x) { return __builtin_amdgcn_rcpf(x); }
__device__ __forceinline__ float ftanh(float x) {
    const float e = __expf(2.0f * x);
    return 1.0f - 2.0f * frcp(e + 1.0f);
}

__global__ __launch_bounds__(256, 4) void mean_kernel(
    const float* __restrict__ x, float* __restrict__ mean)
{
    __shared__ float4 part[256];
    const int tid = threadIdx.x;
    const int bid = blockIdx.x;          // 512 blocks: b = bid>>6, blk = bid&63
    const int b   = bid >> 6;
    const int blk = bid & 63;
    const int cq  = tid >> 6;            // 0..3
    const int pg  = tid & 63;            // 0..63
    const float4* xb = (const float4*)(x + ((size_t)b * 64 + cq * 16) * 16384)
                       + blk * 64 + pg;
    float4 s = make_float4(0.f, 0.f, 0.f, 0.f);
    #pragma unroll
    for (int c = 0; c < 16; ++c) {
        float4 v = xb[(size_t)c * 4096];
        s.x += v.x; s.y += v.y; s.z += v.z; s.w += v.w;
    }
    part[tid] = s;
    __syncthreads();
    if (tid < 64) {
        float4 a = part[tid], b4 = part[64 + tid], c4 = part[128 + tid], d4 = part[192 + tid];
        float4 m = make_float4((a.x + b4.x + c4.x + d4.x) * (1.f / 64),
                               (a.y + b4.y + c4.y + d4.y) * (1.f / 64),
                               (a.z + b4.z + c4.z + d4.z) * (1.f / 64),
                               (a.w + b4.w + c4.w + d4.w) * (1.f / 64));
        ((float4*)(mean + (size_t)b * 16384))[blk * 64 + tid] = m;
    }
}

__global__ __launch_bounds__(512, 4) void carafe_main(
    const float* __restrict__ x,
    const float* __restrict__ mean,
    const float* __restrict__ w_off,
    const float* __restrict__ b_off,
    float* __restrict__ out)
{
    constexpr int H = 128, W = 128, HS = 256, WS = 256;

    __shared__ float4 xs4[16][6][32];   // 16 ch x rows ys0-1..ys0+4 x cols 0..127
    __shared__ float ms[6][130];        // mean rows ys0-1..ys0+4, cols -1..128
    const float2* xs2 = (const float2*)&xs4[0][0][0];   // [16][6][64]

    const int tid = threadIdx.x;
    // XCD swizzle: 1024 blocks = 8 XCD x 128; XCD j owns batch j (all strips
    // + channel groups -> vertical halo rows reused in that XCD's L2).
    const int L  = (blockIdx.x & 7) * 128 + (blockIdx.x >> 3);
    const int b  = L >> 7;
    const int r7 = L & 127;
    const int s  = r7 >> 2;             // strip 0..31 (4 lo-res rows each)
    const int cg = r7 & 3;
    const int ys0 = s * 4;
    const int c0  = cg * 16;

    // ---- issue mean-tile loads (registers) ----
    const float* mb = mean + (size_t)b * (H * W);
    float mval[2];
    #pragma unroll
    for (int it = 0; it < 2; ++it) {
        const int idx = tid + it * 512;
        mval[it] = 0.f;
        if (idx < 780) {                 // 6 rows x 130 cols
            const int r = idx / 130, col = idx - r * 130;
            const int gy = ys0 - 1 + r, gx = col - 1;
            if ((unsigned)gy < (unsigned)H && (unsigned)gx < (unsigned)W)
                mval[it] = mb[gy * W + gx];
        }
    }

    // ---- issue x-strip loads (6 float4/thread, exact 512B rows) ----
    const float* xb = x + ((size_t)b * 64 + c0) * (H * W);
    float4 pf[6];
    #pragma unroll
    for (int it = 0; it < 6; ++it) {
        const int idx = tid + it * 512;  // 0..3071
        const int c   = idx / 192;
        const int rem = idx - c * 192;
        const int r   = rem >> 5;
        const int q4  = rem & 31;
        const int gy  = ys0 - 1 + r;
        pf[it] = ((unsigned)gy < (unsigned)H)
               ? *(const float4*)(xb + (c * H + gy) * W + 4 * q4)
               : make_float4(0.f, 0.f, 0.f, 0.f);
    }

    // ---- write + publish mean tile ----
    #pragma unroll
    for (int it = 0; it < 2; ++it) {
        const int idx = tid + it * 512;
        if (idx < 780) {
            const int r = idx / 130, col = idx - r * 130;
            ms[r][col] = mval[it];
        }
    }
    __syncthreads();

    // ---- weight math (x loads still in flight underneath) ----
    const int hy = tid >> 6;             // 0..7 hi-res row within strip
    const int q  = tid & 63;             // quad: hi-res cols 4q..4q+3
    const int yr = hy >> 1;              // 0..3 lo-res row within strip
    const int podd = hy & 1;
    const int Yg = 8 * s + hy;

    float m[3][4];
    #pragma unroll
    for (int r = 0; r < 3; ++r)
        #pragma unroll
        for (int cl = 0; cl < 4; ++cl)
            m[r][cl] = ms[yr + r][2 * q + cl];   // gx = 2q-1+cl

    float mrp[5][4];
    #pragma unroll
    for (int cl = 0; cl < 4; ++cl) {
        mrp[0][cl] = m[0][cl];
        mrp[1][cl] = podd ? m[1][cl] : m[0][cl];
        mrp[2][cl] = m[1][cl];
        mrp[3][cl] = podd ? m[2][cl] : m[1][cl];
        mrp[4][cl] = m[2][cl];
    }

    // column-aggregated conv coefficients (thread-uniform)
    float ce[2][5][3], co_[2][5][3];
    #pragma unroll
    for (int o = 0; o < 2; ++o)
        #pragma unroll
        for (int p = 0; p < 5; ++p) {
            const float w0 = w_off[o * 25 + p * 5 + 0];
            const float w1 = w_off[o * 25 + p * 5 + 1];
            const float w2 = w_off[o * 25 + p * 5 + 2];
            const float w3 = w_off[o * 25 + p * 5 + 3];
            const float w4 = w_off[o * 25 + p * 5 + 4];
            ce[o][p][0]  = w0 + w1;  ce[o][p][1]  = w2 + w3;  ce[o][p][2]  = w4;
            co_[o][p][0] = w0;       co_[o][p][1] = w1 + w2;  co_[o][p][2] = w3 + w4;
        }

    // edge folding: tap m-col t (0..3) <-> global col 2q-1+t; zero weight
    // where tap is outside the image (only q=0 t=0 and q=63 t=3).
    const float cval0 = (q > 0) ? 1.f : 0.f;
    const float cval3 = (q < 63) ? 1.f : 0.f;
    float cval[4] = {cval0, 1.f, 1.f, cval3};

    const float b0 = b_off[0], b1 = b_off[1];
    float wgt[4][9];
    #pragma unroll
    for (int j = 0; j < 4; ++j) {
        const int d = j >> 1;
        float o0 = 0.f, o1 = 0.f;
        if (j & 1) {
            #pragma unroll
            for (int p = 0; p < 5; ++p)
                #pragma unroll
                for (int tt = 0; tt < 3; ++tt) {
                    o0 = fmaf(co_[0][p][tt], mrp[p][d + tt], o0);
                    o1 = fmaf(co_[1][p][tt], mrp[p][d + tt], o1);
                }
        } else {
            #pragma unroll
            for (int p = 0; p < 5; ++p)
                #pragma unroll
                for (int tt = 0; tt < 3; ++tt) {
                    o0 = fmaf(ce[0][p][tt], mrp[p][d + tt], o0);
                    o1 = fmaf(ce[1][p][tt], mrp[p][d + tt], o1);
                }
        }
        const float off0 = ftanh(o0 + b0) * 0.25f;
        const float off1 = ftanh(o1 + b1) * 0.25f;
        const float s0 = (podd ? 0.25f : -0.25f) + off0;
        const float s1 = ((j & 1) ? 0.25f : -0.25f) + off1;

        const int jc = 1 + d;
        const float mctr = m[1][jc];

        float ssum = 0.f;
        float lg[9];
        #pragma unroll
        for (int k = 0; k < 9; ++k) {
            const int di = k / 3 - 1, dj = k % 3 - 1;
            const float d0 = s0 - (float)di;
            const float d1 = s1 - (float)dj;
            const float kern = frcp(fmaf(d0, d0, fmaf(d1, d1, 0.5f)));
            const float gd = m[1 + di][jc + dj] - mctr;
            const float g  = frcp(fmaf(gd, gd, 1.0f));
            lg[k] = __expf(g * kern);
            ssum += lg[k];
        }
        const float inv = frcp(ssum);
        #pragma unroll
        for (int k = 0; k < 9; ++k) {
            const int dj = k % 3 - 1;
            wgt[j][k] = lg[k] * inv * cval[jc + dj];
        }
    }

    // ---- write + publish x strip ----
    float4* xsl = &xs4[0][0][0];
    #pragma unroll
    for (int it = 0; it < 6; ++it) {
        const int idx = tid + it * 512;
        const int c   = idx / 192;
        const int rem = idx - c * 192;
        xsl[c * 192 + rem] = pf[it];     // rem = r*32+q4, layout matches
    }
    __syncthreads();

    // ---- CARAFE: 16 channels; taps = 3 float2 reads/row; 1KB/wave stores ----
    const int qm = (q > 0)  ? q - 1 : 0;     // garbage ok: weight 0 at edge
    const int qp = (q < 63) ? q + 1 : 63;
    float* ob = out + (((size_t)b * 64 + c0) * HS + Yg) * WS + 4 * q;
    #pragma unroll 4
    for (int c = 0; c < 16; ++c) {
        float xv[3][4];
        #pragma unroll
        for (int r = 0; r < 3; ++r) {
            const int rowb = (c * 6 + yr + r) * 64;
            const float2 f0 = xs2[rowb + qm];
            const float2 f1 = xs2[rowb + q];
            const float2 f2 = xs2[rowb + qp];
            xv[r][0] = f0.y; xv[r][1] = f1.x; xv[r][2] = f1.y; xv[r][3] = f2.x;
        }
        float a[4];
        #pragma unroll
        for (int j = 0; j < 4; ++j) {
            const int px = j >> 1;
            float acc = 0.f;
            #pragma unroll
            for (int di = 0; di < 3; ++di)
                #pragma unroll
                for (int dj = 0; dj < 3; ++dj)
                    acc = fmaf(wgt[j][di * 3 + dj], xv[di][px + dj], acc);
            a[j] = acc;
        }
        *reinterpret_cast<float4*>(ob + (size_t)c * HS * WS) =
            make_float4(a[0], a[1], a[2], a[3]);
    }
}

extern "C" void kernel_launch(void* const* d_in, const int* in_sizes, int n_in,
                              void* d_out, int out_size, void* d_ws, size_t ws_size,
                              hipStream_t stream) {
    const float* x  = (const float*)d_in[0];
    const float* w  = (const float*)d_in[1];
    const float* bo = (const float*)d_in[2];
    float* out  = (float*)d_out;
    float* mean = (float*)d_ws;            // 8*128*128 floats = 512 KB

    mean_kernel<<<512, TB, 0, stream>>>(x, mean);
    // 1024 blocks = 8 batches x 32 strips x 4 channel groups (XCD-swizzled)
    carafe_main<<<1024, 512, 0, stream>>>(x, mean, w, bo, out);
}